// Round 1
// baseline (203.020 us; speedup 1.0000x reference)
//
#include <hip/hip_runtime.h>
#include <cstdint>

#define BLK 256
#define SPB 8                     // samples per block
#define XS_INTS (16 + SPB*240)    // 64B header + SPB * 30 rows * 32B, as ints

// Padded x-sign layout per sample: 30 rows x 32 bytes.
//   rows 0,1            = zero pad (conv rows ih=-2,-1)
//   row (ih+2), byte iw = sign(x[ih][iw]) for ih in 0..27, iw in 0..27
//   bytes 28..31 of each row = zero pad (covers iw=-2,-1 reads wrapping from prev row)
// 64-byte header absorbs the s=0, ih=-2, iw=-2 underflow.

__global__ __launch_bounds__(BLK, 4)
void bnn_fused(const float* __restrict__ x,
               const float* __restrict__ conv_w,
               const float* __restrict__ conv_b,
               const float* __restrict__ bn2_g,
               const float* __restrict__ bn2_b,
               const float* __restrict__ bn2_m,
               const float* __restrict__ bn2_v,
               const float* __restrict__ fc_w,
               const float* __restrict__ fc_b,
               const float* __restrict__ bn1_g,
               const float* __restrict__ bn1_b,
               const float* __restrict__ bn1_m,
               const float* __restrict__ bn1_v,
               float* __restrict__ out)
{
    __shared__ int   xsi[XS_INTS];   // packed sign bytes of x, padded
    __shared__ int   ysi[SPB*32];    // sign(y) bytes, 128B/sample (125 used, pads 0)
    __shared__ int   wmsk[64];       // conv xor-mask words: [ (c*6+kr)*2 + {0,1} ]
    __shared__ int   fmsk[320];      // fc xor-mask words:   [ o*32 + w ]
    __shared__ int   nnegI[8];       // #negative conv weights per channel
    __shared__ int   fnegI[16];      // #negative fc weights per output
    __shared__ float zf[SPB*10];

    const int tid = threadIdx.x;
    const int blk = blockIdx.x;

    // ================= Phase A/B: staging (single sync after) =================
    // Zero ONLY the pad ints of xsi (interior is fully overwritten below,
    // disjoint addresses -> no sync needed between zeroing and filling).
    for (int i = tid; i < 16 + SPB*44; i += BLK) {
        int idx;
        if (i < 16) idx = i;                       // header
        else {
            int j = i - 16; int s = j / 44; int k = j - s*44;
            // k<16: two top pad rows (16 ints); else right-pad int (idx 7) of rows 2..29
            idx = 16 + s*240 + (k < 16 ? k : ((k - 16 + 2)*8 + 7));
        }
        xsi[idx] = 0;
    }
    // Zero ys (so bytes 125..127 of each row are 0 for the int-granular FC dot)
    for (int i = tid; i < SPB*32; i += BLK) ysi[i] = 0;

    // FC xor masks (pad bytes k>=125 get mask 0 -> contribute sext(0^0)=0)
    for (int i = tid; i < 320; i += BLK) {
        int o = i >> 5, w = i & 31;
        uint32_t mm = 0;
        #pragma unroll
        for (int k = 0; k < 4; k++) {
            int kk = w*4 + k;
            if (kk < 125) mm |= (fc_w[o*125 + kk] < 0.f) ? (0xFFu << (8*k)) : 0u;
        }
        fmsk[i] = (int)mm;
    }
    // Conv xor masks: per (channel, kernel-row), 6 weight bytes in 2 words
    if (tid < 30) {
        int c = tid / 6, kr = tid - c*6;
        const float* wp = conv_w + c*36 + kr*6;
        uint32_t m0 = 0, m1 = 0;
        #pragma unroll
        for (int k = 0; k < 4; k++) m0 |= (wp[k]   < 0.f) ? (0xFFu << (8*k)) : 0u;
        #pragma unroll
        for (int k = 0; k < 2; k++) m1 |= (wp[4+k] < 0.f) ? (0xFFu << (8*k)) : 0u;
        wmsk[tid*2 + 0] = (int)m0;
        wmsk[tid*2 + 1] = (int)m1;
    }
    // Negative-weight counts (exact-integer corrections for the xor trick:
    // sext(b^0xFF) = -b-1, so sum = dot - #neg; add #neg back)
    if (tid >= 32 && tid < 37) {
        int c = tid - 32, cnt = 0;
        for (int k = 0; k < 36; k++) cnt += (conv_w[c*36 + k] < 0.f);
        nnegI[c] = cnt;
    }
    if (tid >= 64 && tid < 74) {
        int o = tid - 64, cnt = 0;
        for (int k = 0; k < 125; k++) cnt += (fc_w[o*125 + k] < 0.f);
        fnegI[o] = cnt;
    }
    // Load + binarize x: fully coalesced float4 stream (the 102.8 MB that matters)
    {
        const float4* xg = (const float4*)x + (size_t)blk * (SPB*196);
        for (int i = tid; i < SPB*196; i += BLK) {
            float4 v = xg[i];
            int s = i / 196, rem = i - s*196;
            int r = rem / 7,  cq  = rem - r*7;       // 7 float4 per 28-wide row
            int b0 = (v.x > 0.f) - (v.x < 0.f);
            int b1 = (v.y > 0.f) - (v.y < 0.f);
            int b2 = (v.z > 0.f) - (v.z < 0.f);
            int b3 = (v.w > 0.f) - (v.w < 0.f);
            int packed = (b0 & 0xFF) | ((b1 & 0xFF) << 8) | ((b2 & 0xFF) << 16) | (b3 << 24);
            xsi[16 + s*240 + (r+2)*8 + cq] = packed;
        }
    }
    __syncthreads();

    // ================= Phase C: binarized conv + BN2 + sign =================
    // 250 threads: c = tid/50 fixed per thread -> 12 mask words live in registers.
    if (tid < 250) {
        const int c  = tid / 50;
        const int jb = tid - c*50;
        int m[12];
        #pragma unroll
        for (int i = 0; i < 12; i++) m[i] = wmsk[c*12 + i];
        const int   nneg  = nnegI[c];
        const float cb    = conv_b[c];
        const float mean  = bn2_m[c];
        const float scale = bn2_g[c] / sqrtf(bn2_v[c] + 1e-5f);
        const float beta  = bn2_b[c];
        #pragma unroll
        for (int t = 0; t < (SPB*25)/50; t++) {
            int j  = jb + 50*t;                 // (s,pos) item, covers SPB*25 exactly
            int s  = j / 25, pos = j - s*25;
            int oh = pos / 5, ow  = pos - oh*5;
            // window top-left byte: row (oh*6), col (ow*6 - 2) in padded layout
            int boff = 64 + s*960 + oh*192 + ow*6 - 2;
            int wi = boff >> 2;
            int sh = (boff & 3) * 8;            // 0 or 16
            int acc = 0;
            #pragma unroll
            for (int kr = 0; kr < 6; kr++) {
                uint32_t w0 = (uint32_t)xsi[wi + kr*8];
                uint32_t w1 = (uint32_t)xsi[wi + kr*8 + 1];
                uint64_t vv = ((uint64_t)w1 << 32) | (uint64_t)w0;
                vv >>= sh;                      // low 6 bytes = window row
                uint32_t e0 = (uint32_t)vv         ^ (uint32_t)m[kr*2 + 0];
                uint32_t e1 = (uint32_t)(vv >> 32) ^ (uint32_t)m[kr*2 + 1];
                acc += ((int)(e0 << 24)) >> 24;
                acc += ((int)(e0 << 16)) >> 24;
                acc += ((int)(e0 <<  8)) >> 24;
                acc += ((int)(e0      )) >> 24;
                acc += ((int)(e1 << 24)) >> 24;
                acc += ((int)(e1 << 16)) >> 24;
            }
            float conv = (float)(acc + nneg);   // exact integer conv result
            float yv = ((conv + cb) - mean) * scale + beta;
            // hardtanh clip preserves sign -> sign(clip(y)) == sign(y)
            signed char sb = (signed char)((yv > 0.f) - (yv < 0.f));
            ((signed char*)ysi)[s*128 + c*25 + pos] = sb;
        }
    }
    __syncthreads();

    // ================= Phase D: binarized FC + BN1 =================
    for (int item = tid; item < SPB*10; item += BLK) {
        int s = item / 10, o = item - s*10;
        int acc = 0;
        #pragma unroll
        for (int w = 0; w < 32; w++) {
            uint32_t tb = (uint32_t)ysi[s*32 + w] ^ (uint32_t)fmsk[o*32 + w];
            acc += ((int)(tb << 24)) >> 24;
            acc += ((int)(tb << 16)) >> 24;
            acc += ((int)(tb <<  8)) >> 24;
            acc += ((int)(tb      )) >> 24;
        }
        float z  = (float)(acc + fnegI[o]) + fc_b[o];   // exact int dot + bias
        float sc = bn1_g[o] / sqrtf(bn1_v[o] + 1e-5f);
        zf[item] = (z - bn1_m[o]) * sc + bn1_b[o];
    }
    __syncthreads();

    // ================= Phase E: log_softmax (per sample) =================
    if (tid < SPB) {
        float v[10], mx = -1e30f;
        #pragma unroll
        for (int o = 0; o < 10; o++) { v[o] = zf[tid*10 + o]; mx = fmaxf(mx, v[o]); }
        float l = 0.f;
        #pragma unroll
        for (int o = 0; o < 10; o++) l += __expf(v[o] - mx);
        float lse = mx + __logf(l);
        #pragma unroll
        for (int o = 0; o < 10; o++) zf[tid*10 + o] = v[o] - lse;
    }
    __syncthreads();

    // ================= Phase F: coalesced store =================
    for (int i = tid; i < SPB*10; i += BLK)
        out[(size_t)blk * (SPB*10) + i] = zf[i];
}

extern "C" void kernel_launch(void* const* d_in, const int* in_sizes, int n_in,
                              void* d_out, int out_size, void* d_ws, size_t ws_size,
                              hipStream_t stream)
{
    const float* xp     = (const float*)d_in[0];
    const float* conv_w = (const float*)d_in[1];
    const float* conv_b = (const float*)d_in[2];
    const float* bn2_g  = (const float*)d_in[3];
    const float* bn2_b  = (const float*)d_in[4];
    const float* bn2_m  = (const float*)d_in[5];
    const float* bn2_v  = (const float*)d_in[6];
    const float* fc_w   = (const float*)d_in[7];
    const float* fc_b   = (const float*)d_in[8];
    const float* bn1_g  = (const float*)d_in[9];
    const float* bn1_b  = (const float*)d_in[10];
    const float* bn1_m  = (const float*)d_in[11];
    const float* bn1_v  = (const float*)d_in[12];
    float* outp = (float*)d_out;

    const int B = in_sizes[0] / 784;      // 32768
    const int grid = B / SPB;             // 4096
    bnn_fused<<<grid, BLK, 0, stream>>>(xp, conv_w, conv_b,
                                        bn2_g, bn2_b, bn2_m, bn2_v,
                                        fc_w, fc_b,
                                        bn1_g, bn1_b, bn1_m, bn1_v,
                                        outp);
}

// Round 2
// 179.802 us; speedup vs baseline: 1.1291x; 1.1291x over previous
//
#include <hip/hip_runtime.h>
#include <cstdint>

#define BLK 256
#define SPB 8                      // samples per block
#define RS  9                      // row stride in words (36 B) - breaks pow2 banks
#define SS  (30*RS)                // sample stride in words (270)
#define HDR 16                     // 64 B zero header
#define XS_INTS (HDR + SPB*SS)     // 2176 ints
#define YS_W 33                    // ysi words per sample (132 B, 125 used)

// ---- i8 dot4: v_dot4_i32_i8 if available, exact byte fallback otherwise ----
#if defined(__has_builtin)
# if __has_builtin(__builtin_amdgcn_sdot4)
#  define HAVE_SDOT4 1
# endif
#endif

__device__ __forceinline__ int dot4i8(int a, int b, int c) {
#ifdef HAVE_SDOT4
    return __builtin_amdgcn_sdot4(a, b, c, false);
#else
    int r = c;
    r += (((int)(a << 24)) >> 24) * (((int)(b << 24)) >> 24);
    r += (((int)(a << 16)) >> 24) * (((int)(b << 16)) >> 24);
    r += (((int)(a <<  8)) >> 24) * (((int)(b <<  8)) >> 24);
    r += (a >> 24) * (b >> 24);
    return r;
#endif
}

__device__ __forceinline__ int pack_sign4(float4 v) {
    int b0 = (v.x > 0.f) - (v.x < 0.f);
    int b1 = (v.y > 0.f) - (v.y < 0.f);
    int b2 = (v.z > 0.f) - (v.z < 0.f);
    int b3 = (v.w > 0.f) - (v.w < 0.f);
    return (b0 & 0xFF) | ((b1 & 0xFF) << 8) | ((b2 & 0xFF) << 16) | (b3 << 24);
}

// ws layout (ints): [0..29] conv w bytes0-3 per (c*6+kr); [30..59] bytes4-5 (hi 2 zero)
// [60..389] fc i8 weights, stride 33 (pad word zero); floats: [390..394] conv scale,
// [395..399] conv bias (convb/bn folded); [400..409] fc scale; [410..419] fc bias.
__global__ void bnn_setup(const float* __restrict__ conv_w, const float* __restrict__ conv_b,
                          const float* __restrict__ bn2_g, const float* __restrict__ bn2_b,
                          const float* __restrict__ bn2_m, const float* __restrict__ bn2_v,
                          const float* __restrict__ fc_w,  const float* __restrict__ fc_b,
                          const float* __restrict__ bn1_g, const float* __restrict__ bn1_b,
                          const float* __restrict__ bn1_m, const float* __restrict__ bn1_v,
                          int* __restrict__ ws)
{
    const int tid = threadIdx.x;   // 64 threads
    if (tid < 30) {
        int c = tid / 6, kr = tid - c * 6;
        const float* wp = conv_w + c * 36 + kr * 6;
        uint32_t a = 0, b = 0;
        #pragma unroll
        for (int k = 0; k < 4; k++) { int s = (wp[k]   > 0.f) - (wp[k]   < 0.f); a |= (uint32_t)(s & 0xFF) << (8 * k); }
        #pragma unroll
        for (int k = 0; k < 2; k++) { int s = (wp[4+k] > 0.f) - (wp[4+k] < 0.f); b |= (uint32_t)(s & 0xFF) << (8 * k); }
        ws[tid] = (int)a;
        ws[30 + tid] = (int)b;
    }
    for (int i = tid; i < 330; i += 64) {
        int o = i / 33, w = i - o * 33;
        uint32_t m = 0;
        #pragma unroll
        for (int k = 0; k < 4; k++) {
            int kk = w * 4 + k;
            if (kk < 125) { float f = fc_w[o * 125 + kk]; int s = (f > 0.f) - (f < 0.f); m |= (uint32_t)(s & 0xFF) << (8 * k); }
        }
        ws[60 + i] = (int)m;
    }
    if (tid < 5) {
        float sc = bn2_g[tid] / sqrtf(bn2_v[tid] + 1e-5f);
        ((float*)ws)[390 + tid] = sc;
        ((float*)ws)[395 + tid] = (conv_b[tid] - bn2_m[tid]) * sc + bn2_b[tid];
    }
    if (tid >= 32 && tid < 42) {
        int o = tid - 32;
        float sc = bn1_g[o] / sqrtf(bn1_v[o] + 1e-5f);
        ((float*)ws)[400 + o] = sc;
        ((float*)ws)[410 + o] = (fc_b[o] - bn1_m[o]) * sc + bn1_b[o];
    }
}

__global__ __launch_bounds__(BLK, 4)
void bnn_main(const float* __restrict__ x, const int* __restrict__ ws,
              float* __restrict__ out)
{
    __shared__ int   xsi[XS_INTS];    // padded sign bytes of x (rows 0,1 + word 7,8/row = 0)
    __shared__ int   ysi[SPB * YS_W]; // sign(y) bytes, 132 B/sample (125 used, rest 0)
    __shared__ int   wsS[420];        // cached weights/affines
    __shared__ float zf[SPB * 10];

    const int tid = threadIdx.x;
    const int blk = blockIdx.x;

    // ---- issue all global loads first (independent, pipelined) ----
    const float4* xg = (const float4*)x + (size_t)blk * (SPB * 196);
    float4 v[6]; float4 v6;
    #pragma unroll
    for (int k = 0; k < 6; k++) v[k] = xg[tid + k * BLK];
    const bool has7 = tid < (SPB * 196 - 6 * BLK);     // 1568 = 6*256 + 32
    if (has7) v6 = xg[tid + 6 * BLK];

    for (int i = tid; i < 420; i += BLK) wsS[i] = ws[i];

    // zero ONLY the pad words of xsi (interior fully overwritten, disjoint)
    for (int i = tid; i < HDR + SPB * 74; i += BLK) {
        int idx;
        if (i < HDR) idx = i;
        else {
            int j = i - HDR, s = j / 74, k = j - s * 74;
            idx = HDR + s * SS + (k < 18 ? k : (2 + (k - 18) / 2) * RS + 7 + ((k - 18) & 1));
        }
        xsi[idx] = 0;
    }
    for (int i = tid; i < SPB * YS_W; i += BLK) ysi[i] = 0;

    // ---- binarize + pack into padded LDS layout ----
    #pragma unroll
    for (int k = 0; k < 6; k++) {
        int idx = tid + k * BLK;
        int s = idx / 196, rem = idx - s * 196;
        int r = rem / 7,   cq  = rem - r * 7;
        xsi[HDR + s * SS + (r + 2) * RS + cq] = pack_sign4(v[k]);
    }
    if (has7) {
        int idx = tid + 6 * BLK;
        int s = idx / 196, rem = idx - s * 196;
        int r = rem / 7,   cq  = rem - r * 7;
        xsi[HDR + s * SS + (r + 2) * RS + cq] = pack_sign4(v6);
    }
    __syncthreads();

    // ---- binarized conv (dot4) + folded BN2 + sign ----
    if (tid < 250) {
        const int c  = tid / 50;
        const int jb = tid - c * 50;
        int w0r[6], w1r[6];
        #pragma unroll
        for (int kr = 0; kr < 6; kr++) { w0r[kr] = wsS[c * 6 + kr]; w1r[kr] = wsS[30 + c * 6 + kr]; }
        const float sc = __int_as_float(wsS[390 + c]);
        const float bi = __int_as_float(wsS[395 + c]);
        #pragma unroll
        for (int t = 0; t < (SPB * 25) / 50; t++) {
            int j  = jb + 50 * t;
            int s  = j / 25, pos = j - s * 25;
            int oh = pos / 5, ow  = pos - oh * 5;
            int boff = 64 + s * (SS * 4) + oh * (6 * RS * 4) + ow * 6 - 2;
            int wi = boff >> 2;
            int sh = (boff & 3) * 8;                  // 0 or 16 only
            int acc = 0;
            #pragma unroll
            for (int kr = 0; kr < 6; kr++) {
                uint32_t a0 = (uint32_t)xsi[wi + kr * RS];
                uint32_t a1 = (uint32_t)xsi[wi + kr * RS + 1];
                uint64_t vv = (((uint64_t)a1) << 32) | a0;
                vv >>= sh;
                acc = dot4i8((int)(uint32_t)vv,         w0r[kr], acc);
                acc = dot4i8((int)(uint32_t)(vv >> 32), w1r[kr], acc);
            }
            float yv = (float)acc * sc + bi;          // exact int conv, folded affine
            ((signed char*)ysi)[s * (YS_W * 4) + c * 25 + pos] =
                (signed char)((yv > 0.f) - (yv < 0.f));
        }
    }
    __syncthreads();

    // ---- binarized FC (dot4) + folded BN1 ----
    if (tid < SPB * 10) {
        int s = tid / 10, o = tid - s * 10;
        int acc = 0;
        #pragma unroll
        for (int w = 0; w < 32; w++)
            acc = dot4i8(ysi[s * YS_W + w], wsS[60 + o * 33 + w], acc);
        zf[tid] = (float)acc * __int_as_float(wsS[400 + o]) + __int_as_float(wsS[410 + o]);
    }
    __syncthreads();

    // ---- log_softmax per sample ----
    if (tid < SPB) {
        float vv[10], mx = -1e30f;
        #pragma unroll
        for (int o = 0; o < 10; o++) { vv[o] = zf[tid * 10 + o]; mx = fmaxf(mx, vv[o]); }
        float l = 0.f;
        #pragma unroll
        for (int o = 0; o < 10; o++) l += __expf(vv[o] - mx);
        float lse = mx + __logf(l);
        #pragma unroll
        for (int o = 0; o < 10; o++) zf[tid * 10 + o] = vv[o] - lse;
    }
    __syncthreads();

    // ---- coalesced store ----
    for (int i = tid; i < SPB * 10; i += BLK)
        out[(size_t)blk * (SPB * 10) + i] = zf[i];
}

extern "C" void kernel_launch(void* const* d_in, const int* in_sizes, int n_in,
                              void* d_out, int out_size, void* d_ws, size_t ws_size,
                              hipStream_t stream)
{
    const float* xp     = (const float*)d_in[0];
    const float* conv_w = (const float*)d_in[1];
    const float* conv_b = (const float*)d_in[2];
    const float* bn2_g  = (const float*)d_in[3];
    const float* bn2_b  = (const float*)d_in[4];
    const float* bn2_m  = (const float*)d_in[5];
    const float* bn2_v  = (const float*)d_in[6];
    const float* fc_w   = (const float*)d_in[7];
    const float* fc_b   = (const float*)d_in[8];
    const float* bn1_g  = (const float*)d_in[9];
    const float* bn1_b  = (const float*)d_in[10];
    const float* bn1_m  = (const float*)d_in[11];
    const float* bn1_v  = (const float*)d_in[12];
    float* outp = (float*)d_out;
    int*   ws   = (int*)d_ws;

    const int B = in_sizes[0] / 784;      // 32768
    const int grid = B / SPB;             // 4096

    bnn_setup<<<1, 64, 0, stream>>>(conv_w, conv_b, bn2_g, bn2_b, bn2_m, bn2_v,
                                    fc_w, fc_b, bn1_g, bn1_b, bn1_m, bn1_v, ws);
    bnn_main<<<grid, BLK, 0, stream>>>(xp, ws, outp);
}

// Round 3
// 179.726 us; speedup vs baseline: 1.1296x; 1.0004x over previous
//
#include <hip/hip_runtime.h>
#include <cstdint>

#define BLK 256
#define SPB 16                     // samples per block
#define RS  9                      // row stride in words (36 B) - breaks pow2 banks
#define ROWS 30
#define SS  (ROWS*RS)              // 270 words per sample
#define HDR 16                     // 64 B zero header
#define XS_INTS (HDR + SPB*SS)     // 4336 ints
#define YS_W 33                    // ysi words per sample (132 B, 125 used)
#define NQ  ((SPB*196)/BLK)        // 12 full staging rounds
#define NREM (SPB*196 - NQ*BLK)    // 64 leftover quads

// wsS layout (ints; floats stored via __int_as_float)
#define W0_OFF  0                  // 30: conv w bytes kc0..3 per (c*6+kr)
#define W1P_OFF 30                 // 15: conv w bytes {kc4,kc5} of rows 2p,2p+1 per (c*3+p)
#define FC_OFF  45                 // 330: fc i8 sign words, o*33+w (w<32 meaningful)
#define CSC_OFF 375                // 5: conv folded scale
#define CBI_OFF 380                // 5: conv folded bias
#define FSC_OFF 385                // 10: fc folded scale
#define FBI_OFF 395                // 10: fc folded bias
#define WS_TOT  405

#if defined(__has_builtin)
# if __has_builtin(__builtin_amdgcn_sdot4)
#  define HAVE_SDOT4 1
# endif
#endif

__device__ __forceinline__ int dot4i8(int a, int b, int c) {
#ifdef HAVE_SDOT4
    return __builtin_amdgcn_sdot4(a, b, c, false);
#else
    int r = c;
    r += (((int)(a << 24)) >> 24) * (((int)(b << 24)) >> 24);
    r += (((int)(a << 16)) >> 24) * (((int)(b << 16)) >> 24);
    r += (((int)(a <<  8)) >> 24) * (((int)(b <<  8)) >> 24);
    r += (a >> 24) * (b >> 24);
    return r;
#endif
}

__device__ __forceinline__ int pack_sign4(float4 v) {
    int b0 = (v.x > 0.f) - (v.x < 0.f);
    int b1 = (v.y > 0.f) - (v.y < 0.f);
    int b2 = (v.z > 0.f) - (v.z < 0.f);
    int b3 = (v.w > 0.f) - (v.w < 0.f);
    return (b0 & 0xFF) | ((b1 & 0xFF) << 8) | ((b2 & 0xFF) << 16) | (b3 << 24);
}

__device__ __forceinline__ int sign8(float f) {
    return (f > 0.f) - (f < 0.f);
}

__global__ __launch_bounds__(BLK, 4)
void bnn_fused(const float* __restrict__ x,
               const float* __restrict__ conv_w, const float* __restrict__ conv_b,
               const float* __restrict__ bn2_g,  const float* __restrict__ bn2_b,
               const float* __restrict__ bn2_m,  const float* __restrict__ bn2_v,
               const float* __restrict__ fc_w,   const float* __restrict__ fc_b,
               const float* __restrict__ bn1_g,  const float* __restrict__ bn1_b,
               const float* __restrict__ bn1_m,  const float* __restrict__ bn1_v,
               float* __restrict__ out)
{
    __shared__ int   xsi[XS_INTS];    // padded sign bytes of x
    __shared__ int   ysi[SPB * YS_W]; // sign(y) bytes, 132 B/sample (125 used)
    __shared__ int   wsS[WS_TOT];     // packed weights + folded affines
    __shared__ float zf[SPB * 10];

    const int tid = threadIdx.x;
    const int blk = blockIdx.x;

    // ---- issue all x loads first (independent, pipelined) ----
    const float4* xg = (const float4*)x + (size_t)blk * (SPB * 196);
    float4 v[NQ]; float4 vr;
    #pragma unroll
    for (int k = 0; k < NQ; k++) v[k] = xg[tid + k * BLK];
    const bool has = tid < NREM;
    if (has) vr = xg[tid + NQ * BLK];

    // ---- per-block weight build (tiny, L2-resident) ----
    if (tid < 30) {                       // w0: bytes kc0..3 per (c,kr)
        int c = tid / 6, kr = tid - c * 6;
        const float* wp = conv_w + c * 36 + kr * 6;
        uint32_t a = 0;
        #pragma unroll
        for (int k = 0; k < 4; k++) a |= (uint32_t)(sign8(wp[k]) & 0xFF) << (8 * k);
        wsS[W0_OFF + tid] = (int)a;
    } else if (tid >= 32 && tid < 47) {   // w1p: {kc4,kc5} of rows 2p,2p+1
        int i = tid - 32, c = i / 3, p = i - c * 3;
        const float* wp = conv_w + c * 36;
        uint32_t a = 0;
        a |= (uint32_t)(sign8(wp[(2*p)*6 + 4]) & 0xFF);
        a |= (uint32_t)(sign8(wp[(2*p)*6 + 5]) & 0xFF) << 8;
        a |= (uint32_t)(sign8(wp[(2*p+1)*6 + 4]) & 0xFF) << 16;
        a |= (uint32_t)(sign8(wp[(2*p+1)*6 + 5]) & 0xFF) << 24;
        wsS[W1P_OFF + i] = (int)a;
    } else if (tid >= 48 && tid < 53) {   // conv affines
        int c = tid - 48;
        float sc = bn2_g[c] / sqrtf(bn2_v[c] + 1e-5f);
        wsS[CSC_OFF + c] = __float_as_int(sc);
        wsS[CBI_OFF + c] = __float_as_int((conv_b[c] - bn2_m[c]) * sc + bn2_b[c]);
    } else if (tid >= 64 && tid < 74) {   // fc affines
        int o = tid - 64;
        float sc = bn1_g[o] / sqrtf(bn1_v[o] + 1e-5f);
        wsS[FSC_OFF + o] = __float_as_int(sc);
        wsS[FBI_OFF + o] = __float_as_int((fc_b[o] - bn1_m[o]) * sc + bn1_b[o]);
    }
    for (int i = tid; i < 330; i += BLK) {  // fc sign words
        int o = i / 33, w = i - o * 33;
        uint32_t m = 0;
        #pragma unroll
        for (int k = 0; k < 4; k++) {
            int kk = w * 4 + k;
            if (kk < 125) m |= (uint32_t)(sign8(fc_w[o * 125 + kk]) & 0xFF) << (8 * k);
        }
        wsS[FC_OFF + i] = (int)m;
    }

    // ---- zero ONLY pad words of xsi (interior fully overwritten, disjoint) ----
    for (int i = tid; i < HDR + SPB * 74; i += BLK) {
        int idx;
        if (i < HDR) idx = i;
        else {
            int j = i - HDR, s = j / 74, k = j - s * 74;
            idx = HDR + s * SS + (k < 18 ? k : (2 + (k - 18) / 2) * RS + 7 + ((k - 18) & 1));
        }
        xsi[idx] = 0;
    }
    for (int i = tid; i < SPB * YS_W; i += BLK) ysi[i] = 0;

    // ---- binarize + pack x into padded LDS layout ----
    #pragma unroll
    for (int k = 0; k < NQ; k++) {
        int idx = tid + k * BLK;
        int s = idx / 196, rem = idx - s * 196;
        int r = rem / 7,   cq  = rem - r * 7;
        xsi[HDR + s * SS + (r + 2) * RS + cq] = pack_sign4(v[k]);
    }
    if (has) {
        int idx = tid + NQ * BLK;
        int s = idx / 196, rem = idx - s * 196;
        int r = rem / 7,   cq  = rem - r * 7;
        xsi[HDR + s * SS + (r + 2) * RS + cq] = pack_sign4(vr);
    }
    __syncthreads();

    // ---- conv: thread owns (s,pos), all 5 channels; window read ONCE ----
    {
        int w0[30], w1p[15]; float csc[5], cbi[5];
        #pragma unroll
        for (int i = 0; i < 30; i++) w0[i]  = wsS[W0_OFF + i];
        #pragma unroll
        for (int i = 0; i < 15; i++) w1p[i] = wsS[W1P_OFF + i];
        #pragma unroll
        for (int c = 0; c < 5; c++) {
            csc[c] = __int_as_float(wsS[CSC_OFF + c]);
            cbi[c] = __int_as_float(wsS[CBI_OFF + c]);
        }
        #pragma unroll
        for (int it = 0; it < 2; it++) {
            int j = tid + it * BLK;             // items 0..399 (it1: tid<144)
            if (j < SPB * 25) {
                int s  = j / 25, pos = j - s * 25;
                int oh = pos / 5, ow  = pos - oh * 5;
                int q  = (6 * ow + 2) / 4 - 1;          // word offset of byte (6ow-2)
                int sh = ((6 * ow + 2) & 3) * 8;        // 16,0,16,0,16
                int wi0 = HDR + s * SS + 54 * oh + q;
                uint32_t e0[6], e1[6];
                #pragma unroll
                for (int kr = 0; kr < 6; kr++) {
                    uint32_t a0 = (uint32_t)xsi[wi0 + 9 * kr];
                    uint32_t a1 = (uint32_t)xsi[wi0 + 9 * kr + 1];
                    uint64_t vv = ((((uint64_t)a1) << 32) | a0) >> sh;
                    e0[kr] = (uint32_t)vv;
                    e1[kr] = (uint32_t)(vv >> 32) & 0xFFFFu;
                }
                uint32_t e1p[3];
                #pragma unroll
                for (int p = 0; p < 3; p++) e1p[p] = e1[2*p] | (e1[2*p+1] << 16);
                #pragma unroll
                for (int c = 0; c < 5; c++) {
                    int acc = 0;
                    #pragma unroll
                    for (int kr = 0; kr < 6; kr++) acc = dot4i8((int)e0[kr], w0[c*6+kr], acc);
                    #pragma unroll
                    for (int p = 0; p < 3; p++)    acc = dot4i8((int)e1p[p], w1p[c*3+p], acc);
                    float yv = (float)acc * csc[c] + cbi[c];
                    // hardtanh preserves sign
                    ((signed char*)ysi)[s * (YS_W*4) + c * 25 + pos] = (signed char)sign8(yv);
                }
            }
        }
    }
    __syncthreads();

    // ---- FC: 160 threads, one (s,o) each ----
    if (tid < SPB * 10) {
        int s = tid / 10, o = tid - s * 10;
        int acc = 0;
        #pragma unroll
        for (int w = 0; w < 32; w++)
            acc = dot4i8(ysi[s * YS_W + w], wsS[FC_OFF + o * 33 + w], acc);
        zf[tid] = (float)acc * __int_as_float(wsS[FSC_OFF + o])
                             + __int_as_float(wsS[FBI_OFF + o]);
    }
    __syncthreads();

    // ---- log_softmax per sample ----
    if (tid < SPB) {
        float vv[10], mx = -1e30f;
        #pragma unroll
        for (int o = 0; o < 10; o++) { vv[o] = zf[tid * 10 + o]; mx = fmaxf(mx, vv[o]); }
        float l = 0.f;
        #pragma unroll
        for (int o = 0; o < 10; o++) l += __expf(vv[o] - mx);
        float lse = mx + __logf(l);
        #pragma unroll
        for (int o = 0; o < 10; o++) zf[tid * 10 + o] = vv[o] - lse;
    }
    __syncthreads();

    // ---- coalesced store ----
    for (int i = tid; i < SPB * 10; i += BLK)
        out[(size_t)blk * (SPB * 10) + i] = zf[i];
}

extern "C" void kernel_launch(void* const* d_in, const int* in_sizes, int n_in,
                              void* d_out, int out_size, void* d_ws, size_t ws_size,
                              hipStream_t stream)
{
    const float* xp     = (const float*)d_in[0];
    const float* conv_w = (const float*)d_in[1];
    const float* conv_b = (const float*)d_in[2];
    const float* bn2_g  = (const float*)d_in[3];
    const float* bn2_b  = (const float*)d_in[4];
    const float* bn2_m  = (const float*)d_in[5];
    const float* bn2_v  = (const float*)d_in[6];
    const float* fc_w   = (const float*)d_in[7];
    const float* fc_b   = (const float*)d_in[8];
    const float* bn1_g  = (const float*)d_in[9];
    const float* bn1_b  = (const float*)d_in[10];
    const float* bn1_m  = (const float*)d_in[11];
    const float* bn1_v  = (const float*)d_in[12];
    float* outp = (float*)d_out;

    const int B = in_sizes[0] / 784;      // 32768
    const int grid = B / SPB;             // 2048
    bnn_fused<<<grid, BLK, 0, stream>>>(xp, conv_w, conv_b,
                                        bn2_g, bn2_b, bn2_m, bn2_v,
                                        fc_w, fc_b, bn1_g, bn1_b, bn1_m, bn1_v,
                                        outp);
}